// Round 8
// baseline (201.533 us; speedup 1.0000x reference)
//
#include <hip/hip_runtime.h>
#include <hip/hip_fp16.h>

#define N_NODES 100000
#define N_EDGES 1600000
#define DIN 128
#define NH 4
#define ND 32
#define HD 128   // NH*ND
#define NEG_SLOPE 0.2f
#define SCAN_NB 98     // ceil(N_NODES / 1024)
#define MROWS 64       // gemm rows per block
#define APAD 136       // halves per LDS row (128 + 8 pad)
#define GEMM_BLOCKS ((N_NODES + MROWS - 1) / MROWS)   // 1563
#define GEPB 1024      // edges counted per gemm block (1563*1024 >= E)

typedef _Float16 half8_t __attribute__((ext_vector_type(8)));
typedef float f32x4 __attribute__((ext_vector_type(4)));

__device__ __forceinline__ float lrelu(float x) {
    return x > 0.0f ? x : NEG_SLOPE * x;
}

union Pack8  { uint2 u; __half2 h2[2]; };
union Pack16 { uint4 u; __half2 h2[4]; };

// ---------------- init: zero deg ------------------------------------------
__global__ void k_init(int* __restrict__ deg) {
    int i = blockIdx.x * blockDim.x + threadIdx.x;
    int stride = gridDim.x * blockDim.x;
    for (int j = i; j < N_NODES; j += stride) deg[j] = 0;
}

// ---------------- init (fallback path): zero out + denom ------------------
__global__ void k_init_fb(float* __restrict__ out, float* __restrict__ denom) {
    int i = blockIdx.x * blockDim.x + threadIdx.x;
    int stride = gridDim.x * blockDim.x;
    for (int j = i; j < N_NODES * HD; j += stride) out[j] = 0.0f;
    for (int j = i; j < N_NODES * NH; j += stride) denom[j] = 0.0f;
}

// ---------------- W -> Wt fp16 transposed [c][k] --------------------------
__global__ __launch_bounds__(256) void k_wconv(const float* __restrict__ W,
                                               __half* __restrict__ Wt) {
    int i = blockIdx.x * 256 + threadIdx.x;   // 0..16383
    int k = i >> 7, c = i & 127;
    Wt[c * DIN + k] = __float2half(W[k * HD + c]);
}

// ---------------- MFMA GEMM h = feat @ W (fp16), fused el/er + edge count -
// block 256 = 4 waves; tile 64 rows x 128 cols; wave w: rows w*16..+15.
// v_mfma_f32_16x16x32_f16: A row=l%16,k=8*(l/16)+j; B col=l%16 same k;
// D col=l%16,row=4*(l/16)+r.
__global__ __launch_bounds__(256) void k_gemm(
    const float* __restrict__ feat, const __half* __restrict__ Wt,
    const float* __restrict__ attn_l, const float* __restrict__ attn_r,
    __half* __restrict__ hhalf, float* __restrict__ el, float* __restrict__ er,
    const int* __restrict__ dst, int* __restrict__ deg, int* __restrict__ rank) {

    __shared__ __half As[MROWS * APAD];  // 17408 B (A tile, then C tile)
    __shared__ __half Bs[HD * APAD];     // 34816 B

    const int tid = threadIdx.x;
    const int row0 = blockIdx.x * MROWS;

    // ---- early-issue edge count: atomic latency hides under MFMA ----
    int cr0 = 0, cr1 = 0, cr2 = 0, cr3 = 0;
    int e0 = blockIdx.x * GEPB + tid * 4;
    bool edo = (deg != nullptr) && (e0 < N_EDGES);
    if (edo) {
        int4 d4 = *(const int4*)(dst + e0);
        cr0 = atomicAdd(deg + d4.x, 1);
        cr1 = atomicAdd(deg + d4.y, 1);
        cr2 = atomicAdd(deg + d4.z, 1);
        cr3 = atomicAdd(deg + d4.w, 1);
    }

    // ---- stage Wt -> Bs (2048 uint4) ----
    {
        const uint4* Wv = (const uint4*)Wt;
#pragma unroll
        for (int i = 0; i < 8; ++i) {
            int idx = tid + i * 256;
            int c = idx >> 4, k8 = idx & 15;
            *(uint4*)(&Bs[c * APAD + k8 * 8]) = Wv[idx];
        }
    }
    // ---- stage feat -> As fp16 (2048 float4 -> 8B writes) ----
    {
#pragma unroll
        for (int i = 0; i < 8; ++i) {
            int idx = tid + i * 256;
            int r = idx >> 5, c4 = idx & 31;
            int row = row0 + r;
            float4 f = (row < N_NODES)
                ? *(const float4*)(feat + (size_t)row * DIN + c4 * 4)
                : make_float4(0.0f, 0.0f, 0.0f, 0.0f);
            Pack8 pk;
            pk.h2[0] = __floats2half2_rn(f.x, f.y);
            pk.h2[1] = __floats2half2_rn(f.z, f.w);
            *(uint2*)(&As[r * APAD + c4 * 4]) = pk.u;
        }
    }
    __syncthreads();

    const int l = tid & 63;
    const int wv = tid >> 6;
    const int lrow = l & 15;
    const int kid = l >> 4;

    f32x4 acc[8];
#pragma unroll
    for (int n = 0; n < 8; ++n) acc[n] = (f32x4){0.0f, 0.0f, 0.0f, 0.0f};

#pragma unroll
    for (int kb = 0; kb < 4; ++kb) {
        half8_t a = *(const half8_t*)(&As[(wv * 16 + lrow) * APAD + kb * 32 + kid * 8]);
#pragma unroll
        for (int n = 0; n < 8; ++n) {
            half8_t b = *(const half8_t*)(&Bs[(n * 16 + lrow) * APAD + kb * 32 + kid * 8]);
            acc[n] = __builtin_amdgcn_mfma_f32_16x16x32_f16(a, b, acc[n], 0, 0, 0);
        }
    }

    // ---- C -> LDS (reuse As) as fp16 [row][col], pad stride ----
    __syncthreads();
#pragma unroll
    for (int n = 0; n < 8; ++n)
#pragma unroll
        for (int r = 0; r < 4; ++r)
            As[(wv * 16 + kid * 4 + r) * APAD + n * 16 + lrow] =
                __float2half(acc[n][r]);
    __syncthreads();

    // ---- epilogue: thread = (row = tid>>2, head = tid&3) ----
    {
        int lr = tid >> 2;
        int row = row0 + lr;
        int head = tid & 3;
        if (row < N_NODES) {
            float suml = 0.0f, sumr = 0.0f;
#pragma unroll
            for (int q = 0; q < 4; ++q) {
                Pack16 p;
                p.u = *(const uint4*)(&As[lr * APAD + head * 32 + q * 8]);
                float4 al0 = *(const float4*)(attn_l + head * 32 + q * 8);
                float4 al1 = *(const float4*)(attn_l + head * 32 + q * 8 + 4);
                float4 ar0 = *(const float4*)(attn_r + head * 32 + q * 8);
                float4 ar1 = *(const float4*)(attn_r + head * 32 + q * 8 + 4);
                float2 x0 = __half22float2(p.h2[0]);
                float2 x1 = __half22float2(p.h2[1]);
                float2 x2 = __half22float2(p.h2[2]);
                float2 x3 = __half22float2(p.h2[3]);
                suml += x0.x * al0.x + x0.y * al0.y + x1.x * al0.z + x1.y * al0.w;
                suml += x2.x * al1.x + x2.y * al1.y + x3.x * al1.z + x3.y * al1.w;
                sumr += x0.x * ar0.x + x0.y * ar0.y + x1.x * ar0.z + x1.y * ar0.w;
                sumr += x2.x * ar1.x + x2.y * ar1.y + x3.x * ar1.z + x3.y * ar1.w;
                *(uint4*)(hhalf + (size_t)row * HD + head * 32 + q * 8) = p.u;
            }
            el[(size_t)row * NH + head] = suml;
            er[(size_t)row * NH + head] = sumr;
        }
    }

    // ---- write ranks (atomic results now long since returned) ----
    if (edo) *(int4*)(rank + e0) = make_int4(cr0, cr1, cr2, cr3);
}

// ---------------- scan: deg -> rowptr (exclusive) ------------------------
__global__ __launch_bounds__(256) void k_scanA(const int* __restrict__ deg,
                                               int* __restrict__ bsum) {
    __shared__ int wsum[4];
    int b = blockIdx.x, tid = threadIdx.x;
    int base = b * 1024 + tid * 4;
    int s = 0;
#pragma unroll
    for (int j = 0; j < 4; ++j) {
        int i = base + j;
        if (i < N_NODES) s += deg[i];
    }
#pragma unroll
    for (int off = 32; off >= 1; off >>= 1) s += __shfl_down(s, off, 64);
    if ((tid & 63) == 0) wsum[tid >> 6] = s;
    __syncthreads();
    if (tid == 0) bsum[b] = wsum[0] + wsum[1] + wsum[2] + wsum[3];
}

__global__ __launch_bounds__(128) void k_scanB(const int* __restrict__ bsum,
                                               int* __restrict__ boff) {
    __shared__ int tmp[SCAN_NB];
    int tid = threadIdx.x;
    if (tid < SCAN_NB) tmp[tid] = bsum[tid];
    __syncthreads();
    if (tid == 0) {
        int acc = 0;
        for (int i = 0; i < SCAN_NB; ++i) { int v = tmp[i]; tmp[i] = acc; acc += v; }
    }
    __syncthreads();
    if (tid < SCAN_NB) boff[tid] = tmp[tid];
}

__global__ __launch_bounds__(256) void k_scanC(const int* __restrict__ deg,
                                               const int* __restrict__ boff,
                                               int* __restrict__ rowptr) {
    __shared__ int wtot[4];
    int b = blockIdx.x, tid = threadIdx.x;
    int base = b * 1024 + tid * 4;
    int d[4];
#pragma unroll
    for (int j = 0; j < 4; ++j) {
        int i = base + j;
        d[j] = (i < N_NODES) ? deg[i] : 0;
    }
    int tsum = d[0] + d[1] + d[2] + d[3];
    int lane = tid & 63;
    int v = tsum;
#pragma unroll
    for (int off = 1; off < 64; off <<= 1) {
        int t = __shfl_up(v, off, 64);
        if (lane >= off) v += t;
    }
    if (lane == 63) wtot[tid >> 6] = v;
    int texcl = v - tsum;
    __syncthreads();
    int woff = 0;
    for (int w = 0; w < (tid >> 6); ++w) woff += wtot[w];
    int pfx = boff[b] + woff + texcl;
#pragma unroll
    for (int j = 0; j < 4; ++j) {
        int i = base + j;
        if (i < N_NODES) rowptr[i] = pfx;
        else if (i == N_NODES) rowptr[i] = pfx;
        pfx += d[j];
    }
}

// ---------------- scatter: sorted-by-dst src index ONLY (4 B/edge) -------
__global__ __launch_bounds__(256) void k_scatter(
    const int* __restrict__ src, const int* __restrict__ dst,
    const int* __restrict__ rank, const int* __restrict__ rowptr,
    int* __restrict__ srcs) {
    int e = blockIdx.x * blockDim.x + threadIdx.x;
    if (e >= N_EDGES) return;
    int d = dst[e];
    srcs[rowptr[d] + rank[e]] = src[e];
}

// ---------------- CSR gather-aggregate (single pass) ----------------------
// One 64-lane wave per dst node. lane = grp<<4 | cl; grp = 4-way edge
// parallelism, cl covers channels cl*8..cl*8+7 (half8 = 16 B load).
__global__ __launch_bounds__(256) void k_agg_csr(
    const int* __restrict__ rowptr, const int* __restrict__ srcs,
    const float* __restrict__ el, const float* __restrict__ er,
    const __half* __restrict__ hhalf, float* __restrict__ out) {
    int node = blockIdx.x * 4 + (threadIdx.x >> 6);
    int lane = threadIdx.x & 63;
    int grp = lane >> 4;
    int cl = lane & 15;
    int head = cl >> 2;
    int beg = rowptr[node], end = rowptr[node + 1];

    const float er_h = er[(size_t)node * NH + head];

    float dsum = 0.0f;
    float a[8];
#pragma unroll
    for (int q = 0; q < 8; ++q) a[q] = 0.0f;

    int i = beg + grp;
    for (; i + 4 < end; i += 8) {
        int s0 = srcs[i];
        int s1 = srcs[i + 4];
        float w0 = __expf(lrelu(el[(size_t)s0 * NH + head] + er_h));
        float w1 = __expf(lrelu(el[(size_t)s1 * NH + head] + er_h));
        Pack16 p0, p1;
        p0.u = *(const uint4*)(hhalf + (size_t)s0 * HD + cl * 8);
        p1.u = *(const uint4*)(hhalf + (size_t)s1 * HD + cl * 8);
        dsum += w0 + w1;
#pragma unroll
        for (int q = 0; q < 4; ++q) {
            float2 x0 = __half22float2(p0.h2[q]);
            float2 x1 = __half22float2(p1.h2[q]);
            a[2 * q]     = fmaf(x0.x, w0, a[2 * q]);
            a[2 * q + 1] = fmaf(x0.y, w0, a[2 * q + 1]);
            a[2 * q]     = fmaf(x1.x, w1, a[2 * q]);
            a[2 * q + 1] = fmaf(x1.y, w1, a[2 * q + 1]);
        }
    }
    if (i < end) {
        int s0 = srcs[i];
        float w0 = __expf(lrelu(el[(size_t)s0 * NH + head] + er_h));
        Pack16 p0;
        p0.u = *(const uint4*)(hhalf + (size_t)s0 * HD + cl * 8);
        dsum += w0;
#pragma unroll
        for (int q = 0; q < 4; ++q) {
            float2 x0 = __half22float2(p0.h2[q]);
            a[2 * q]     = fmaf(x0.x, w0, a[2 * q]);
            a[2 * q + 1] = fmaf(x0.y, w0, a[2 * q + 1]);
        }
    }

    dsum += __shfl_xor(dsum, 16, 64);
    dsum += __shfl_xor(dsum, 32, 64);
#pragma unroll
    for (int q = 0; q < 8; ++q) {
        a[q] += __shfl_xor(a[q], 16, 64);
        a[q] += __shfl_xor(a[q], 32, 64);
    }

    if (grp == 0) {
        float inv = (end > beg) ? 1.0f / dsum : 0.0f;
        *(float4*)(out + (size_t)node * HD + cl * 8) =
            make_float4(a[0] * inv, a[1] * inv, a[2] * inv, a[3] * inv);
        *(float4*)(out + (size_t)node * HD + cl * 8 + 4) =
            make_float4(a[4] * inv, a[5] * inv, a[6] * inv, a[7] * inv);
    }
}

// ---------------- fallback path (atomics) --------------------------------
__global__ __launch_bounds__(256) void k_denom_fb(
    const int* __restrict__ src, const int* __restrict__ dst,
    const float* __restrict__ el, const float* __restrict__ er,
    float* __restrict__ denom) {
    int e = blockIdx.x * blockDim.x + threadIdx.x;
    if (e >= N_EDGES) return;
    int s = src[e], d = dst[e];
    float4 l = *(const float4*)(el + (size_t)s * NH);
    float4 r = *(const float4*)(er + (size_t)d * NH);
    float* dn = denom + (size_t)d * NH;
    atomicAdd(dn + 0, __expf(lrelu(l.x + r.x)));
    atomicAdd(dn + 1, __expf(lrelu(l.y + r.y)));
    atomicAdd(dn + 2, __expf(lrelu(l.z + r.z)));
    atomicAdd(dn + 3, __expf(lrelu(l.w + r.w)));
}

__global__ __launch_bounds__(256) void k_agg_fb(
    const int* __restrict__ src, const int* __restrict__ dst,
    const float* __restrict__ el, const float* __restrict__ er,
    const float* __restrict__ denom, const __half* __restrict__ hhalf,
    float* __restrict__ out) {
    long long t = (long long)blockIdx.x * blockDim.x + threadIdx.x;
    if (t >= (long long)N_EDGES * HD) return;
    int e = (int)(t >> 7);
    int c = (int)(t & 127);
    int hh = c >> 5;
    int s = src[e], d = dst[e];
    float x = lrelu(el[(size_t)s * NH + hh] + er[(size_t)d * NH + hh]);
    float a = __expf(x) / denom[(size_t)d * NH + hh];
    atomicAdd(out + (size_t)d * HD + c,
              __half2float(hhalf[(size_t)s * HD + c]) * a);
}

extern "C" void kernel_launch(void* const* d_in, const int* in_sizes, int n_in,
                              void* d_out, int out_size, void* d_ws, size_t ws_size,
                              hipStream_t stream) {
    const float* feat   = (const float*)d_in[0];
    const int*   src    = (const int*)d_in[1];
    const int*   dst    = (const int*)d_in[2];
    const float* W      = (const float*)d_in[3];
    const float* attn_l = (const float*)d_in[4];
    const float* attn_r = (const float*)d_in[5];
    float* out = (float*)d_out;

    char* base = (char*)d_ws;
    size_t off = 0;
    auto take = [&](size_t bytes) -> char* {
        char* r = base + off;
        off = (off + bytes + 255) & ~(size_t)255;
        return r;
    };
    __half* hhalf = (__half*)take((size_t)N_NODES * HD * 2);
    float* el     = (float*)take((size_t)N_NODES * NH * 4);
    float* er     = (float*)take((size_t)N_NODES * NH * 4);
    int*   deg    = (int*)take((size_t)N_NODES * 4);
    int*   rowptr = (int*)take((size_t)(N_NODES + 1) * 4);
    int*   rank   = (int*)take((size_t)N_EDGES * 4);
    int*   bsum   = (int*)take(SCAN_NB * 4);
    int*   boff   = (int*)take(SCAN_NB * 4);
    int*   srcs   = (int*)take((size_t)N_EDGES * 4);
    __half* Wt    = (__half*)take((size_t)DIN * HD * 2);
    float* denom  = (float*)take((size_t)N_NODES * NH * 4); // fallback only
    bool csr = (off <= ws_size);

    int eb = (N_EDGES + 255) / 256;

    if (csr) {
        k_init<<<128, 256, 0, stream>>>(deg);
        k_wconv<<<64, 256, 0, stream>>>(W, Wt);
        k_gemm<<<GEMM_BLOCKS, 256, 0, stream>>>(feat, Wt, attn_l, attn_r,
                                                hhalf, el, er, dst, deg, rank);
        k_scanA<<<SCAN_NB, 256, 0, stream>>>(deg, bsum);
        k_scanB<<<1, 128, 0, stream>>>(bsum, boff);
        k_scanC<<<SCAN_NB, 256, 0, stream>>>(deg, boff, rowptr);
        k_scatter<<<eb, 256, 0, stream>>>(src, dst, rank, rowptr, srcs);
        k_agg_csr<<<N_NODES / 4, 256, 0, stream>>>(rowptr, srcs, el, er, hhalf, out);
    } else {
        k_init_fb<<<2048, 256, 0, stream>>>(out, denom);
        k_wconv<<<64, 256, 0, stream>>>(W, Wt);
        k_gemm<<<GEMM_BLOCKS, 256, 0, stream>>>(feat, Wt, attn_l, attn_r,
                                                hhalf, el, er, dst,
                                                (int*)nullptr, (int*)nullptr);
        k_denom_fb<<<eb, 256, 0, stream>>>(src, dst, el, er, denom);
        long long tot = (long long)N_EDGES * HD;
        int ab = (int)((tot + 255) / 256);
        k_agg_fb<<<ab, 256, 0, stream>>>(src, dst, el, er, denom, hhalf, out);
    }
}

// Round 9
// 170.804 us; speedup vs baseline: 1.1799x; 1.1799x over previous
//
#include <hip/hip_runtime.h>
#include <hip/hip_fp16.h>

#define N_NODES 100000
#define N_EDGES 1600000
#define DIN 128
#define NH 4
#define ND 32
#define HD 128   // NH*ND
#define NEG_SLOPE 0.2f
#define MROWS 64       // gemm rows per block
#define APAD 136       // halves per LDS row (128 + 8 pad)
#define GEMM_BLOCKS ((N_NODES + MROWS - 1) / MROWS)   // 1563

// ---- bucket sort geometry ----
#define NBUCK 782      // ceil(N_NODES / 128) coarse buckets (dst>>7)
#define CHB 2048       // edges per hist/scatter block
#define NHB 782        // hist blocks: 782*2048 = 1,601,536 >= E

typedef _Float16 half8_t __attribute__((ext_vector_type(8)));
typedef float f32x4 __attribute__((ext_vector_type(4)));

__device__ __forceinline__ float lrelu(float x) {
    return x > 0.0f ? x : NEG_SLOPE * x;
}

union Pack8  { uint2 u; __half2 h2[2]; };
union Pack16 { uint4 u; __half2 h2[4]; };

// ---------------- W -> Wt fp16 transposed [c][k] --------------------------
__global__ __launch_bounds__(256) void k_wconv(const float* __restrict__ W,
                                               __half* __restrict__ Wt) {
    int i = blockIdx.x * 256 + threadIdx.x;   // 0..16383
    int k = i >> 7, c = i & 127;
    Wt[c * DIN + k] = __float2half(W[k * HD + c]);
}

// ---------------- MFMA GEMM h = feat @ W (fp16), fused el/er --------------
// block 256 = 4 waves; tile 64 rows x 128 cols; wave w: rows w*16..+15.
// v_mfma_f32_16x16x32_f16: A row=l%16,k=8*(l/16)+j; B col=l%16 same k;
// D col=l%16,row=4*(l/16)+r.
__global__ __launch_bounds__(256) void k_gemm(
    const float* __restrict__ feat, const __half* __restrict__ Wt,
    const float* __restrict__ attn_l, const float* __restrict__ attn_r,
    __half* __restrict__ hhalf, float* __restrict__ el, float* __restrict__ er) {

    __shared__ __half As[MROWS * APAD];  // 17408 B (A tile, then C tile)
    __shared__ __half Bs[HD * APAD];     // 34816 B

    const int tid = threadIdx.x;
    const int row0 = blockIdx.x * MROWS;

    // ---- stage Wt -> Bs (2048 uint4) ----
    {
        const uint4* Wv = (const uint4*)Wt;
#pragma unroll
        for (int i = 0; i < 8; ++i) {
            int idx = tid + i * 256;
            int c = idx >> 4, k8 = idx & 15;
            *(uint4*)(&Bs[c * APAD + k8 * 8]) = Wv[idx];
        }
    }
    // ---- stage feat -> As fp16 ----
    {
#pragma unroll
        for (int i = 0; i < 8; ++i) {
            int idx = tid + i * 256;
            int r = idx >> 5, c4 = idx & 31;
            int row = row0 + r;
            float4 f = (row < N_NODES)
                ? *(const float4*)(feat + (size_t)row * DIN + c4 * 4)
                : make_float4(0.0f, 0.0f, 0.0f, 0.0f);
            Pack8 pk;
            pk.h2[0] = __floats2half2_rn(f.x, f.y);
            pk.h2[1] = __floats2half2_rn(f.z, f.w);
            *(uint2*)(&As[r * APAD + c4 * 4]) = pk.u;
        }
    }
    __syncthreads();

    const int l = tid & 63;
    const int wv = tid >> 6;
    const int lrow = l & 15;
    const int kid = l >> 4;

    f32x4 acc[8];
#pragma unroll
    for (int n = 0; n < 8; ++n) acc[n] = (f32x4){0.0f, 0.0f, 0.0f, 0.0f};

#pragma unroll
    for (int kb = 0; kb < 4; ++kb) {
        half8_t a = *(const half8_t*)(&As[(wv * 16 + lrow) * APAD + kb * 32 + kid * 8]);
#pragma unroll
        for (int n = 0; n < 8; ++n) {
            half8_t b = *(const half8_t*)(&Bs[(n * 16 + lrow) * APAD + kb * 32 + kid * 8]);
            acc[n] = __builtin_amdgcn_mfma_f32_16x16x32_f16(a, b, acc[n], 0, 0, 0);
        }
    }

    // ---- C -> LDS (reuse As) as fp16 [row][col] ----
    __syncthreads();
#pragma unroll
    for (int n = 0; n < 8; ++n)
#pragma unroll
        for (int r = 0; r < 4; ++r)
            As[(wv * 16 + kid * 4 + r) * APAD + n * 16 + lrow] =
                __float2half(acc[n][r]);
    __syncthreads();

    // ---- epilogue: thread = (row = tid>>2, head = tid&3) ----
    {
        int lr = tid >> 2;
        int row = row0 + lr;
        int head = tid & 3;
        if (row < N_NODES) {
            float suml = 0.0f, sumr = 0.0f;
#pragma unroll
            for (int q = 0; q < 4; ++q) {
                Pack16 p;
                p.u = *(const uint4*)(&As[lr * APAD + head * 32 + q * 8]);
                float4 al0 = *(const float4*)(attn_l + head * 32 + q * 8);
                float4 al1 = *(const float4*)(attn_l + head * 32 + q * 8 + 4);
                float4 ar0 = *(const float4*)(attn_r + head * 32 + q * 8);
                float4 ar1 = *(const float4*)(attn_r + head * 32 + q * 8 + 4);
                float2 x0 = __half22float2(p.h2[0]);
                float2 x1 = __half22float2(p.h2[1]);
                float2 x2 = __half22float2(p.h2[2]);
                float2 x3 = __half22float2(p.h2[3]);
                suml += x0.x * al0.x + x0.y * al0.y + x1.x * al0.z + x1.y * al0.w;
                suml += x2.x * al1.x + x2.y * al1.y + x3.x * al1.z + x3.y * al1.w;
                sumr += x0.x * ar0.x + x0.y * ar0.y + x1.x * ar0.z + x1.y * ar0.w;
                sumr += x2.x * ar1.x + x2.y * ar1.y + x3.x * ar1.z + x3.y * ar1.w;
                *(uint4*)(hhalf + (size_t)row * HD + head * 32 + q * 8) = p.u;
            }
            el[(size_t)row * NH + head] = suml;
            er[(size_t)row * NH + head] = sumr;
        }
    }
}

// ---------------- bucket sort phase A: coarse LDS histogram ---------------
__global__ __launch_bounds__(256) void k_hist(const int* __restrict__ dst,
                                              int* __restrict__ hist) {
    __shared__ int cnt[NBUCK];
    int tid = threadIdx.x;
    for (int i = tid; i < NBUCK; i += 256) cnt[i] = 0;
    __syncthreads();
    int base = blockIdx.x * CHB;
#pragma unroll
    for (int j = 0; j < 8; ++j) {
        int e = base + j * 256 + tid;
        if (e < N_EDGES) atomicAdd(&cnt[dst[e] >> 7], 1);
    }
    __syncthreads();
    int* hrow = hist + (size_t)blockIdx.x * NBUCK;
    for (int i = tid; i < NBUCK; i += 256) hrow[i] = cnt[i];
}

// ---------------- phase B1: per-bucket column scan (in place) -------------
// block b: exclusive-scan hist[blk][b] over blk=0..NHB-1; tot[b] = sum.
__global__ __launch_bounds__(256) void k_scanH(int* __restrict__ hist,
                                               int* __restrict__ tot) {
    __shared__ int wtot[4];
    int b = blockIdx.x, tid = threadIdx.x;
    int idx0 = tid * 4;
    int v[4];
#pragma unroll
    for (int j = 0; j < 4; ++j) {
        int blk = idx0 + j;
        v[j] = (blk < NHB) ? hist[(size_t)blk * NBUCK + b] : 0;
    }
    int s = v[0] + v[1] + v[2] + v[3];
    int lane = tid & 63;
    int incl = s;
#pragma unroll
    for (int off = 1; off < 64; off <<= 1) {
        int t = __shfl_up(incl, off, 64);
        if (lane >= off) incl += t;
    }
    if (lane == 63) wtot[tid >> 6] = incl;
    __syncthreads();
    int woff = 0;
    for (int w = 0; w < (tid >> 6); ++w) woff += wtot[w];
    int run = woff + incl - s;
#pragma unroll
    for (int j = 0; j < 4; ++j) {
        int blk = idx0 + j;
        if (blk < NHB) {
            int old = v[j];
            hist[(size_t)blk * NBUCK + b] = run;
            run += old;
        }
    }
    if (tid == 0) tot[b] = wtot[0] + wtot[1] + wtot[2] + wtot[3];
}

// ---------------- phase B2: scan bucket totals -> bucket_base -------------
__global__ __launch_bounds__(256) void k_scanT(const int* __restrict__ tot,
                                               int* __restrict__ bucket_base,
                                               int* __restrict__ rowptr) {
    __shared__ int wtot[4];
    int tid = threadIdx.x;
    int idx0 = tid * 4;
    int v[4];
#pragma unroll
    for (int j = 0; j < 4; ++j) {
        int b = idx0 + j;
        v[j] = (b < NBUCK) ? tot[b] : 0;
    }
    int s = v[0] + v[1] + v[2] + v[3];
    int lane = tid & 63;
    int incl = s;
#pragma unroll
    for (int off = 1; off < 64; off <<= 1) {
        int t = __shfl_up(incl, off, 64);
        if (lane >= off) incl += t;
    }
    if (lane == 63) wtot[tid >> 6] = incl;
    __syncthreads();
    int woff = 0;
    for (int w = 0; w < (tid >> 6); ++w) woff += wtot[w];
    int run = woff + incl - s;
#pragma unroll
    for (int j = 0; j < 4; ++j) {
        int b = idx0 + j;
        if (b < NBUCK) {
            int old = v[j];
            bucket_base[b] = run;
            run += old;
        }
    }
    if (tid == 0) {
        int total = wtot[0] + wtot[1] + wtot[2] + wtot[3];
        bucket_base[NBUCK] = total;
        rowptr[N_NODES] = total;
    }
}

// ---------------- phase C: coarse scatter (LDS cursors, no gl atomics) ----
// packed = src | (dst&127)<<17
__global__ __launch_bounds__(256) void k_cscat(
    const int* __restrict__ src, const int* __restrict__ dst,
    const int* __restrict__ hist, const int* __restrict__ bucket_base,
    int* __restrict__ bucketed) {
    __shared__ int cur[NBUCK];
    int tid = threadIdx.x;
    const int* hrow = hist + (size_t)blockIdx.x * NBUCK;
    for (int i = tid; i < NBUCK; i += 256) cur[i] = bucket_base[i] + hrow[i];
    __syncthreads();
    int base = blockIdx.x * CHB;
#pragma unroll
    for (int j = 0; j < 8; ++j) {
        int e = base + j * 256 + tid;
        if (e < N_EDGES) {
            int d = dst[e];
            int slot = atomicAdd(&cur[d >> 7], 1);
            bucketed[slot] = src[e] | ((d & 127) << 17);
        }
    }
}

// ---------------- phase D: fine sort within bucket + rowptr ---------------
__global__ __launch_bounds__(256) void k_fine(
    const int* __restrict__ bucketed, const int* __restrict__ bucket_base,
    int* __restrict__ srcs, int* __restrict__ rowptr) {
    __shared__ int ecnt[128];
    __shared__ int noff[128];
    int b = blockIdx.x, tid = threadIdx.x;
    int beg = bucket_base[b], end = bucket_base[b + 1];
    if (tid < 128) ecnt[tid] = 0;
    __syncthreads();
    for (int e = beg + tid; e < end; e += 256)
        atomicAdd(&ecnt[bucketed[e] >> 17], 1);
    __syncthreads();
    if (tid == 0) {
        int r = 0;
        for (int i = 0; i < 128; ++i) { noff[i] = r; r += ecnt[i]; }
    }
    __syncthreads();
    int nb = b * 128;
    int nn = N_NODES - nb; if (nn > 128) nn = 128;
    if (tid < nn) rowptr[nb + tid] = beg + noff[tid];
    __syncthreads();
    for (int e = beg + tid; e < end; e += 256) {
        int p = bucketed[e];
        int slot = beg + atomicAdd(&noff[p >> 17], 1);
        srcs[slot] = p & 0x1FFFF;
    }
}

// ---------------- CSR gather-aggregate (single pass) ----------------------
// One 64-lane wave per dst node. lane = grp<<4 | cl; grp = 4-way edge
// parallelism, cl covers channels cl*8..cl*8+7 (half8 = 16 B load).
__global__ __launch_bounds__(256) void k_agg_csr(
    const int* __restrict__ rowptr, const int* __restrict__ srcs,
    const float* __restrict__ el, const float* __restrict__ er,
    const __half* __restrict__ hhalf, float* __restrict__ out) {
    int node = blockIdx.x * 4 + (threadIdx.x >> 6);
    int lane = threadIdx.x & 63;
    int grp = lane >> 4;
    int cl = lane & 15;
    int head = cl >> 2;
    int beg = rowptr[node], end = rowptr[node + 1];

    const float er_h = er[(size_t)node * NH + head];

    float dsum = 0.0f;
    float a[8];
#pragma unroll
    for (int q = 0; q < 8; ++q) a[q] = 0.0f;

    int i = beg + grp;
    for (; i + 4 < end; i += 8) {
        int s0 = srcs[i];
        int s1 = srcs[i + 4];
        float w0 = __expf(lrelu(el[(size_t)s0 * NH + head] + er_h));
        float w1 = __expf(lrelu(el[(size_t)s1 * NH + head] + er_h));
        Pack16 p0, p1;
        p0.u = *(const uint4*)(hhalf + (size_t)s0 * HD + cl * 8);
        p1.u = *(const uint4*)(hhalf + (size_t)s1 * HD + cl * 8);
        dsum += w0 + w1;
#pragma unroll
        for (int q = 0; q < 4; ++q) {
            float2 x0 = __half22float2(p0.h2[q]);
            float2 x1 = __half22float2(p1.h2[q]);
            a[2 * q]     = fmaf(x0.x, w0, a[2 * q]);
            a[2 * q + 1] = fmaf(x0.y, w0, a[2 * q + 1]);
            a[2 * q]     = fmaf(x1.x, w1, a[2 * q]);
            a[2 * q + 1] = fmaf(x1.y, w1, a[2 * q + 1]);
        }
    }
    if (i < end) {
        int s0 = srcs[i];
        float w0 = __expf(lrelu(el[(size_t)s0 * NH + head] + er_h));
        Pack16 p0;
        p0.u = *(const uint4*)(hhalf + (size_t)s0 * HD + cl * 8);
        dsum += w0;
#pragma unroll
        for (int q = 0; q < 4; ++q) {
            float2 x0 = __half22float2(p0.h2[q]);
            a[2 * q]     = fmaf(x0.x, w0, a[2 * q]);
            a[2 * q + 1] = fmaf(x0.y, w0, a[2 * q + 1]);
        }
    }

    dsum += __shfl_xor(dsum, 16, 64);
    dsum += __shfl_xor(dsum, 32, 64);
#pragma unroll
    for (int q = 0; q < 8; ++q) {
        a[q] += __shfl_xor(a[q], 16, 64);
        a[q] += __shfl_xor(a[q], 32, 64);
    }

    if (grp == 0) {
        float inv = (end > beg) ? 1.0f / dsum : 0.0f;
        *(float4*)(out + (size_t)node * HD + cl * 8) =
            make_float4(a[0] * inv, a[1] * inv, a[2] * inv, a[3] * inv);
        *(float4*)(out + (size_t)node * HD + cl * 8 + 4) =
            make_float4(a[4] * inv, a[5] * inv, a[6] * inv, a[7] * inv);
    }
}

// ---------------- fallback path (atomics) --------------------------------
__global__ void k_init_fb(float* __restrict__ out, float* __restrict__ denom) {
    int i = blockIdx.x * blockDim.x + threadIdx.x;
    int stride = gridDim.x * blockDim.x;
    for (int j = i; j < N_NODES * HD; j += stride) out[j] = 0.0f;
    for (int j = i; j < N_NODES * NH; j += stride) denom[j] = 0.0f;
}

__global__ __launch_bounds__(256) void k_denom_fb(
    const int* __restrict__ src, const int* __restrict__ dst,
    const float* __restrict__ el, const float* __restrict__ er,
    float* __restrict__ denom) {
    int e = blockIdx.x * blockDim.x + threadIdx.x;
    if (e >= N_EDGES) return;
    int s = src[e], d = dst[e];
    float4 l = *(const float4*)(el + (size_t)s * NH);
    float4 r = *(const float4*)(er + (size_t)d * NH);
    float* dn = denom + (size_t)d * NH;
    atomicAdd(dn + 0, __expf(lrelu(l.x + r.x)));
    atomicAdd(dn + 1, __expf(lrelu(l.y + r.y)));
    atomicAdd(dn + 2, __expf(lrelu(l.z + r.z)));
    atomicAdd(dn + 3, __expf(lrelu(l.w + r.w)));
}

__global__ __launch_bounds__(256) void k_agg_fb(
    const int* __restrict__ src, const int* __restrict__ dst,
    const float* __restrict__ el, const float* __restrict__ er,
    const float* __restrict__ denom, const __half* __restrict__ hhalf,
    float* __restrict__ out) {
    long long t = (long long)blockIdx.x * blockDim.x + threadIdx.x;
    if (t >= (long long)N_EDGES * HD) return;
    int e = (int)(t >> 7);
    int c = (int)(t & 127);
    int hh = c >> 5;
    int s = src[e], d = dst[e];
    float x = lrelu(el[(size_t)s * NH + hh] + er[(size_t)d * NH + hh]);
    float a = __expf(x) / denom[(size_t)d * NH + hh];
    atomicAdd(out + (size_t)d * HD + c,
              __half2float(hhalf[(size_t)s * HD + c]) * a);
}

extern "C" void kernel_launch(void* const* d_in, const int* in_sizes, int n_in,
                              void* d_out, int out_size, void* d_ws, size_t ws_size,
                              hipStream_t stream) {
    const float* feat   = (const float*)d_in[0];
    const int*   src    = (const int*)d_in[1];
    const int*   dst    = (const int*)d_in[2];
    const float* W      = (const float*)d_in[3];
    const float* attn_l = (const float*)d_in[4];
    const float* attn_r = (const float*)d_in[5];
    float* out = (float*)d_out;

    char* base = (char*)d_ws;
    size_t off = 0;
    auto take = [&](size_t bytes) -> char* {
        char* r = base + off;
        off = (off + bytes + 255) & ~(size_t)255;
        return r;
    };
    __half* hhalf  = (__half*)take((size_t)N_NODES * HD * 2);
    float* el      = (float*)take((size_t)N_NODES * NH * 4);
    float* er      = (float*)take((size_t)N_NODES * NH * 4);
    __half* Wt     = (__half*)take((size_t)DIN * HD * 2);
    int*  hist     = (int*)take((size_t)NHB * NBUCK * 4);
    int*  tot      = (int*)take((size_t)NBUCK * 4);
    int*  bbase    = (int*)take((size_t)(NBUCK + 1) * 4);
    int*  bucketed = (int*)take((size_t)N_EDGES * 4);
    int*  srcs     = (int*)take((size_t)N_EDGES * 4);
    int*  rowptr   = (int*)take((size_t)(N_NODES + 1) * 4);
    float* denom   = (float*)take((size_t)N_NODES * NH * 4); // fallback only
    bool csr = (off <= ws_size);

    if (csr) {
        k_wconv<<<64, 256, 0, stream>>>(W, Wt);
        k_gemm<<<GEMM_BLOCKS, 256, 0, stream>>>(feat, Wt, attn_l, attn_r,
                                                hhalf, el, er);
        k_hist<<<NHB, 256, 0, stream>>>(dst, hist);
        k_scanH<<<NBUCK, 256, 0, stream>>>(hist, tot);
        k_scanT<<<1, 256, 0, stream>>>(tot, bbase, rowptr);
        k_cscat<<<NHB, 256, 0, stream>>>(src, dst, hist, bbase, bucketed);
        k_fine<<<NBUCK, 256, 0, stream>>>(bucketed, bbase, srcs, rowptr);
        k_agg_csr<<<N_NODES / 4, 256, 0, stream>>>(rowptr, srcs, el, er, hhalf, out);
    } else {
        int eb = (N_EDGES + 255) / 256;
        k_init_fb<<<2048, 256, 0, stream>>>(out, denom);
        k_wconv<<<64, 256, 0, stream>>>(W, Wt);
        k_gemm<<<GEMM_BLOCKS, 256, 0, stream>>>(feat, Wt, attn_l, attn_r,
                                                hhalf, el, er);
        k_denom_fb<<<eb, 256, 0, stream>>>(src, dst, el, er, denom);
        long long totw = (long long)N_EDGES * HD;
        int ab = (int)((totw + 255) / 256);
        k_agg_fb<<<ab, 256, 0, stream>>>(src, dst, el, er, denom, hhalf, out);
    }
}